// Round 1
// baseline (918.768 us; speedup 1.0000x reference)
//
#include <hip/hip_runtime.h>

#define HD 128

// ---------------- degree / dinv ----------------
__global__ __launch_bounds__(256) void k_deg_init(int* degi, int n) {
  int i = blockIdx.x * 256 + threadIdx.x;
  if (i < n) degi[i] = 1;  // self-loop
}

__global__ __launch_bounds__(256) void k_count(const int* __restrict__ dst, int E, int* degi) {
  int i = blockIdx.x * 256 + threadIdx.x;
  if (i < E) atomicAdd(&degi[dst[i]], 1);
}

__global__ __launch_bounds__(256) void k_dinv(const int* __restrict__ degi, float* dinv, int n) {
  int i = blockIdx.x * 256 + threadIdx.x;
  if (i < n) dinv[i] = 1.0f / sqrtf((float)degi[i]);
}

// ---------------- exclusive scan of (degi[i]-1) -> rowptr ----------------
__global__ __launch_bounds__(1024) void k_scan1(const int* __restrict__ degi, int n,
                                                int* rowptr, int* bsum) {
  __shared__ int tmp[1024];
  int i = blockIdx.x * 1024 + threadIdx.x;
  int v = (i < n) ? (degi[i] - 1) : 0;
  tmp[threadIdx.x] = v;
  __syncthreads();
  for (int off = 1; off < 1024; off <<= 1) {
    int t = (threadIdx.x >= off) ? tmp[threadIdx.x - off] : 0;
    __syncthreads();
    tmp[threadIdx.x] += t;
    __syncthreads();
  }
  if (i < n) rowptr[i] = tmp[threadIdx.x] - v;          // exclusive (pre block-offset)
  if (threadIdx.x == 1023) bsum[blockIdx.x] = tmp[1023]; // block total
}

__global__ __launch_bounds__(128) void k_scan2(int* bsum, int nb) {
  __shared__ int tmp[128];
  int v = (threadIdx.x < nb) ? bsum[threadIdx.x] : 0;
  tmp[threadIdx.x] = v;
  __syncthreads();
  for (int off = 1; off < 128; off <<= 1) {
    int t = (threadIdx.x >= off) ? tmp[threadIdx.x - off] : 0;
    __syncthreads();
    tmp[threadIdx.x] += t;
    __syncthreads();
  }
  if (threadIdx.x < nb) bsum[threadIdx.x] = tmp[threadIdx.x] - v; // exclusive, in-place
}

__global__ __launch_bounds__(1024) void k_scan3(int* rowptr, const int* __restrict__ bsum,
                                                int n, int Etot) {
  int i = blockIdx.x * 1024 + threadIdx.x;
  if (i < n) rowptr[i] += bsum[blockIdx.x];
  if (i == 0) rowptr[n] = Etot;
}

// ---------------- CSR fill ----------------
__global__ __launch_bounds__(256) void k_fill(const int* __restrict__ src, const int* __restrict__ dst,
                                              int E, const int* __restrict__ rowptr, int* cursor,
                                              const float* __restrict__ dinv,
                                              int* col, float* nrm) {
  int i = blockIdx.x * 256 + threadIdx.x;
  if (i >= E) return;
  int s = src[i], d = dst[i];
  int pos = rowptr[d] + atomicAdd(&cursor[d], 1);
  col[pos] = s;
  nrm[pos] = dinv[s] * dinv[d];
}

// ---------------- embedding gather ----------------
__global__ __launch_bounds__(256) void k_embed(const int* __restrict__ z,
                                               const float4* __restrict__ emb,
                                               float4* __restrict__ x, int n) {
  int idx = blockIdx.x * 256 + threadIdx.x;
  if (idx >= n * 32) return;
  int node = idx >> 5, q = idx & 31;
  x[idx] = emb[(size_t)z[node] * 32 + q];
}

// ---------------- GEMM: Y[n,128] = X[n,128] @ W[128,128] ----------------
#define FMA4(ACC, S, WV) \
  ACC.x = fmaf(S, WV.x, ACC.x); ACC.y = fmaf(S, WV.y, ACC.y); \
  ACC.z = fmaf(S, WV.z, ACC.z); ACC.w = fmaf(S, WV.w, ACC.w);

__global__ __launch_bounds__(256) void k_gemm(const float* __restrict__ X,
                                              const float* __restrict__ W,
                                              float* __restrict__ Y, int n) {
  __shared__ float4 Wl[128 * 32];  // 64 KB
  const float4* W4 = (const float4*)W;
  for (int i = threadIdx.x; i < 128 * 32; i += 256) Wl[i] = W4[i];
  __syncthreads();
  int tx = threadIdx.x & 31, ty = threadIdx.x >> 5;
  int rbase = blockIdx.x * 64 + ty * 8;
  float4 acc[8];
#pragma unroll
  for (int r = 0; r < 8; ++r) acc[r] = make_float4(0.f, 0.f, 0.f, 0.f);
  const float4* Arow[8];
#pragma unroll
  for (int r = 0; r < 8; ++r) {
    int rr = rbase + r;
    if (rr > n - 1) rr = n - 1;              // clamp loads; stores guarded below
    Arow[r] = (const float4*)(X + (size_t)rr * HD);
  }
  for (int k4 = 0; k4 < 32; ++k4) {
    float4 w0 = Wl[(k4 * 4 + 0) * 32 + tx];
    float4 w1 = Wl[(k4 * 4 + 1) * 32 + tx];
    float4 w2 = Wl[(k4 * 4 + 2) * 32 + tx];
    float4 w3 = Wl[(k4 * 4 + 3) * 32 + tx];
#pragma unroll
    for (int r = 0; r < 8; ++r) {
      float4 a = Arow[r][k4];
      FMA4(acc[r], a.x, w0)
      FMA4(acc[r], a.y, w1)
      FMA4(acc[r], a.z, w2)
      FMA4(acc[r], a.w, w3)
    }
  }
#pragma unroll
  for (int r = 0; r < 8; ++r) {
    int rr = rbase + r;
    if (rr < n) ((float4*)(Y + (size_t)rr * HD))[tx] = acc[r];
  }
}

// ---------------- aggregate: Out[d] = dinv[d]^2*Ht[d] + sum nrm*Ht[src] (+bias, relu) --------
__global__ __launch_bounds__(256) void k_agg(const float* __restrict__ Ht,
                                             const int* __restrict__ rowptr,
                                             const int* __restrict__ col,
                                             const float* __restrict__ nrm,
                                             const float* __restrict__ dinv,
                                             const float* __restrict__ bias,
                                             float* __restrict__ Out, int n, int relu) {
  int node = blockIdx.x * 4 + (threadIdx.x >> 6);
  if (node >= n) return;
  int lane = threadIdx.x & 63;
  float di = dinv[node];
  float w = di * di;
  float2 s = ((const float2*)(Ht + (size_t)node * HD))[lane];
  float accx = s.x * w, accy = s.y * w;
  int e = rowptr[node], end = rowptr[node + 1];
  for (; e < end; ++e) {
    int c = col[e];
    float nv = nrm[e];
    float2 v = ((const float2*)(Ht + (size_t)c * HD))[lane];
    accx = fmaf(nv, v.x, accx);
    accy = fmaf(nv, v.y, accy);
  }
  float2 b = ((const float2*)bias)[lane];
  accx += b.x; accy += b.y;
  if (relu) { accx = fmaxf(accx, 0.f); accy = fmaxf(accy, 0.f); }
  float2 o; o.x = accx; o.y = accy;
  ((float2*)(Out + (size_t)node * HD))[lane] = o;
}

// ---------------- center indices ----------------
__global__ __launch_bounds__(256) void k_ci(const int* __restrict__ batch, int n, int* ci) {
  int i = blockIdx.x * 256 + threadIdx.x;
  if (i >= n) return;
  if (i == 0 || batch[i] != batch[i - 1]) ci[batch[i]] = i;
}

// ---------------- head: out[g] = relu(xs@W1+b1)@W2 + b2, xs = x[ci]*x[ci+1] ----------------
__global__ __launch_bounds__(128) void k_head(const float* __restrict__ X,
                                              const int* __restrict__ ci,
                                              const float* __restrict__ W1,
                                              const float* __restrict__ b1,
                                              const float* __restrict__ w2,
                                              const float* __restrict__ b2,
                                              float* __restrict__ out, int G) {
  __shared__ float xs[HD];
  __shared__ float red[HD];
  int g = blockIdx.x;
  int t = threadIdx.x;
  int c = ci[g];
  xs[t] = X[(size_t)c * HD + t] * X[(size_t)(c + 1) * HD + t];
  __syncthreads();
  float acc = b1[t];
#pragma unroll 8
  for (int k = 0; k < HD; ++k) acc = fmaf(xs[k], W1[k * HD + t], acc);
  acc = fmaxf(acc, 0.f);
  red[t] = acc * w2[t];
  __syncthreads();
  for (int off = 64; off > 0; off >>= 1) {
    if (t < off) red[t] += red[t + off];
    __syncthreads();
  }
  if (t == 0) out[g] = red[0] + b2[0];
}

extern "C" void kernel_launch(void* const* d_in, const int* in_sizes, int n_in,
                              void* d_out, int out_size, void* d_ws, size_t ws_size,
                              hipStream_t stream) {
  (void)n_in; (void)ws_size;
  // inputs (setup_inputs order): num_nodes, z, edge_index, batch, z_emb_table,
  //                              conv_w, conv_b, mlp_w1, mlp_b1, mlp_w2, mlp_b2
  const int*   z      = (const int*)d_in[1];
  const int*   ei     = (const int*)d_in[2];
  const int*   batch  = (const int*)d_in[3];
  const float* emb    = (const float*)d_in[4];
  const float* conv_w = (const float*)d_in[5];
  const float* conv_b = (const float*)d_in[6];
  const float* w1     = (const float*)d_in[7];
  const float* b1     = (const float*)d_in[8];
  const float* w2     = (const float*)d_in[9];
  const float* b2     = (const float*)d_in[10];
  int n = in_sizes[1];
  int E = in_sizes[2] / 2;
  int G = out_size;
  const int* esrc = ei;
  const int* edst = ei + E;

  // workspace carve-up (~117 MB total)
  char* p = (char*)d_ws;
  auto alloc = [&](size_t bytes) { void* r = (void*)p; p += (bytes + 255) / 256 * 256; return r; };
  float* bufA   = (float*)alloc((size_t)n * HD * 4);
  float* bufB   = (float*)alloc((size_t)n * HD * 4);
  int*   degi   = (int*)alloc((size_t)n * 4);
  float* dinv   = (float*)alloc((size_t)n * 4);
  int*   rowptr = (int*)alloc((size_t)(n + 1) * 4);
  int*   cursor = (int*)alloc((size_t)n * 4);
  int*   col    = (int*)alloc((size_t)E * 4);
  float* nrm    = (float*)alloc((size_t)E * 4);
  int*   bsum   = (int*)alloc(1024 * 4);
  int*   ci     = (int*)alloc((size_t)G * 4);

  int nb1024 = (n + 1023) / 1024;  // 98 for N=100000 (k_scan2 supports <=128)

  k_deg_init<<<(n + 255) / 256, 256, 0, stream>>>(degi, n);
  k_count<<<(E + 255) / 256, 256, 0, stream>>>(edst, E, degi);
  k_dinv<<<(n + 255) / 256, 256, 0, stream>>>(degi, dinv, n);
  k_scan1<<<nb1024, 1024, 0, stream>>>(degi, n, rowptr, bsum);
  k_scan2<<<1, 128, 0, stream>>>(bsum, nb1024);
  k_scan3<<<nb1024, 1024, 0, stream>>>(rowptr, bsum, n, E);
  hipMemsetAsync(cursor, 0, (size_t)n * 4, stream);
  k_fill<<<(E + 255) / 256, 256, 0, stream>>>(esrc, edst, E, rowptr, cursor, dinv, col, nrm);
  k_embed<<<(n * 32 + 255) / 256, 256, 0, stream>>>(z, (const float4*)emb, (float4*)bufA, n);

  for (int l = 0; l < 3; ++l) {
    k_gemm<<<(n + 63) / 64, 256, 0, stream>>>(bufA, conv_w + (size_t)l * HD * HD, bufB, n);
    k_agg<<<(n + 3) / 4, 256, 0, stream>>>(bufB, rowptr, col, nrm, dinv,
                                           conv_b + (size_t)l * HD, bufA, n, l < 2 ? 1 : 0);
  }

  k_ci<<<(n + 255) / 256, 256, 0, stream>>>(batch, n, ci);
  k_head<<<G, 128, 0, stream>>>(bufA, ci, w1, b1, w2, b2, (float*)d_out, G);
}

// Round 2
// 687.404 us; speedup vs baseline: 1.3366x; 1.3366x over previous
//
#include <hip/hip_runtime.h>
#include <hip/hip_fp16.h>

#define HD 128

__device__ inline unsigned pack_h2(float x, float y) {
  __half2 h = __floats2half2_rn(x, y);
  return __builtin_bit_cast(unsigned, h);
}
__device__ inline float2 up_h2(unsigned u) {
  __half2 h = __builtin_bit_cast(__half2, u);
  return __half22float2(h);
}

// ---------------- degree / dinv ----------------
__global__ __launch_bounds__(256) void k_deg_init(int* degi, int n) {
  int i = blockIdx.x * 256 + threadIdx.x;
  if (i < n) degi[i] = 1;  // self-loop
}

__global__ __launch_bounds__(256) void k_count(const int* __restrict__ dst, int E, int* degi) {
  int i = blockIdx.x * 256 + threadIdx.x;
  if (i < E) atomicAdd(&degi[dst[i]], 1);
}

__global__ __launch_bounds__(256) void k_dinv(const int* __restrict__ degi, float* dinv, int n) {
  int i = blockIdx.x * 256 + threadIdx.x;
  if (i < n) dinv[i] = 1.0f / sqrtf((float)degi[i]);
}

// ---------------- exclusive scan of (degi[i]-1) -> rowptr ----------------
__global__ __launch_bounds__(1024) void k_scan1(const int* __restrict__ degi, int n,
                                                int* rowptr, int* bsum) {
  __shared__ int tmp[1024];
  int i = blockIdx.x * 1024 + threadIdx.x;
  int v = (i < n) ? (degi[i] - 1) : 0;
  tmp[threadIdx.x] = v;
  __syncthreads();
  for (int off = 1; off < 1024; off <<= 1) {
    int t = (threadIdx.x >= off) ? tmp[threadIdx.x - off] : 0;
    __syncthreads();
    tmp[threadIdx.x] += t;
    __syncthreads();
  }
  if (i < n) rowptr[i] = tmp[threadIdx.x] - v;
  if (threadIdx.x == 1023) bsum[blockIdx.x] = tmp[1023];
}

__global__ __launch_bounds__(128) void k_scan2(int* bsum, int nb) {
  __shared__ int tmp[128];
  int v = (threadIdx.x < nb) ? bsum[threadIdx.x] : 0;
  tmp[threadIdx.x] = v;
  __syncthreads();
  for (int off = 1; off < 128; off <<= 1) {
    int t = (threadIdx.x >= off) ? tmp[threadIdx.x - off] : 0;
    __syncthreads();
    tmp[threadIdx.x] += t;
    __syncthreads();
  }
  if (threadIdx.x < nb) bsum[threadIdx.x] = tmp[threadIdx.x] - v;
}

__global__ __launch_bounds__(1024) void k_scan3(int* rowptr, const int* __restrict__ bsum,
                                                int n, int Etot) {
  int i = blockIdx.x * 1024 + threadIdx.x;
  if (i < n) rowptr[i] += bsum[blockIdx.x];
  if (i == 0) rowptr[n] = Etot;
}

// ---------------- CSR fill ----------------
__global__ __launch_bounds__(256) void k_fill(const int* __restrict__ src, const int* __restrict__ dst,
                                              int E, const int* __restrict__ rowptr, int* cursor,
                                              const float* __restrict__ dinv,
                                              int* col, float* nrm) {
  int i = blockIdx.x * 256 + threadIdx.x;
  if (i >= E) return;
  int s = src[i], d = dst[i];
  int pos = rowptr[d] + atomicAdd(&cursor[d], 1);
  col[pos] = s;
  nrm[pos] = dinv[s] * dinv[d];
}

// ---------------- embedding gather -> half ----------------
__global__ __launch_bounds__(256) void k_embed(const int* __restrict__ z,
                                               const float4* __restrict__ emb,
                                               uint2* __restrict__ xh, int n) {
  int idx = blockIdx.x * 256 + threadIdx.x;
  if (idx >= n * 32) return;
  int node = idx >> 5, q = idx & 31;
  float4 v = emb[(size_t)z[node] * 32 + q];
  uint2 o;
  o.x = pack_h2(v.x, v.y);
  o.y = pack_h2(v.z, v.w);
  xh[idx] = o;
}

// ---------------- GEMM: Yh[n,128] = Xh[n,128] @ W[128,128] (fp32 acc) ----------------
#define FMA4(ACC, S, WV) \
  ACC.x = fmaf(S, WV.x, ACC.x); ACC.y = fmaf(S, WV.y, ACC.y); \
  ACC.z = fmaf(S, WV.z, ACC.z); ACC.w = fmaf(S, WV.w, ACC.w);

__global__ __launch_bounds__(256) void k_gemm(const uint2* __restrict__ Xh,
                                              const float* __restrict__ W,
                                              uint2* __restrict__ Yh, int n) {
  __shared__ float4 Wl[128 * 32];  // 64 KB fp32
  const float4* W4 = (const float4*)W;
  for (int i = threadIdx.x; i < 128 * 32; i += 256) Wl[i] = W4[i];
  __syncthreads();
  int tx = threadIdx.x & 31, ty = threadIdx.x >> 5;
  int rbase = blockIdx.x * 64 + ty * 8;
  float4 acc[8];
#pragma unroll
  for (int r = 0; r < 8; ++r) acc[r] = make_float4(0.f, 0.f, 0.f, 0.f);
  const uint2* Arow[8];
#pragma unroll
  for (int r = 0; r < 8; ++r) {
    int rr = rbase + r;
    if (rr > n - 1) rr = n - 1;  // clamp loads; stores guarded below
    Arow[r] = Xh + (size_t)rr * 32;
  }
  for (int k4 = 0; k4 < 32; ++k4) {
    float4 w0 = Wl[(k4 * 4 + 0) * 32 + tx];
    float4 w1 = Wl[(k4 * 4 + 1) * 32 + tx];
    float4 w2 = Wl[(k4 * 4 + 2) * 32 + tx];
    float4 w3 = Wl[(k4 * 4 + 3) * 32 + tx];
#pragma unroll
    for (int r = 0; r < 8; ++r) {
      uint2 a = Arow[r][k4];
      float2 f01 = up_h2(a.x);
      float2 f23 = up_h2(a.y);
      FMA4(acc[r], f01.x, w0)
      FMA4(acc[r], f01.y, w1)
      FMA4(acc[r], f23.x, w2)
      FMA4(acc[r], f23.y, w3)
    }
  }
#pragma unroll
  for (int r = 0; r < 8; ++r) {
    int rr = rbase + r;
    if (rr < n) {
      uint2 o;
      o.x = pack_h2(acc[r].x, acc[r].y);
      o.y = pack_h2(acc[r].z, acc[r].w);
      Yh[(size_t)rr * 32 + tx] = o;
    }
  }
}

// ------- aggregate: Out[d] = dinv[d]^2*Ht[d] + sum nrm*Ht[src] (+bias, relu), half in/out -----
__global__ __launch_bounds__(256) void k_agg(const unsigned* __restrict__ H,  // half2 rows
                                             const int* __restrict__ rowptr,
                                             const int* __restrict__ col,
                                             const float* __restrict__ nrm,
                                             const float* __restrict__ dinv,
                                             const float* __restrict__ bias,
                                             unsigned* __restrict__ Out, int n, int relu) {
  int node = blockIdx.x * 4 + (threadIdx.x >> 6);
  if (node >= n) return;
  int lane = threadIdx.x & 63;
  float di = dinv[node];
  float w = di * di;
  float2 s = up_h2(H[(size_t)node * 64 + lane]);
  float accx = s.x * w, accy = s.y * w;
  int e = rowptr[node], end = rowptr[node + 1];
  for (; e + 1 < end; e += 2) {
    int c0 = col[e], c1 = col[e + 1];
    float n0 = nrm[e], n1 = nrm[e + 1];
    float2 v0 = up_h2(H[(size_t)c0 * 64 + lane]);
    float2 v1 = up_h2(H[(size_t)c1 * 64 + lane]);
    accx = fmaf(n0, v0.x, accx); accy = fmaf(n0, v0.y, accy);
    accx = fmaf(n1, v1.x, accx); accy = fmaf(n1, v1.y, accy);
  }
  if (e < end) {
    int c0 = col[e];
    float n0 = nrm[e];
    float2 v0 = up_h2(H[(size_t)c0 * 64 + lane]);
    accx = fmaf(n0, v0.x, accx); accy = fmaf(n0, v0.y, accy);
  }
  float2 b = ((const float2*)bias)[lane];
  accx += b.x; accy += b.y;
  if (relu) { accx = fmaxf(accx, 0.f); accy = fmaxf(accy, 0.f); }
  Out[(size_t)node * 64 + lane] = pack_h2(accx, accy);
}

// ---------------- center indices ----------------
__global__ __launch_bounds__(256) void k_ci(const int* __restrict__ batch, int n, int* ci) {
  int i = blockIdx.x * 256 + threadIdx.x;
  if (i >= n) return;
  if (i == 0 || batch[i] != batch[i - 1]) ci[batch[i]] = i;
}

// ---------------- head ----------------
__global__ __launch_bounds__(128) void k_head(const __half* __restrict__ X,
                                              const int* __restrict__ ci,
                                              const float* __restrict__ W1,
                                              const float* __restrict__ b1,
                                              const float* __restrict__ w2,
                                              const float* __restrict__ b2,
                                              float* __restrict__ out, int G) {
  __shared__ float xs[HD];
  __shared__ float red[HD];
  int g = blockIdx.x;
  int t = threadIdx.x;
  int c = ci[g];
  xs[t] = __half2float(X[(size_t)c * HD + t]) * __half2float(X[(size_t)(c + 1) * HD + t]);
  __syncthreads();
  float acc = b1[t];
#pragma unroll 8
  for (int k = 0; k < HD; ++k) acc = fmaf(xs[k], W1[k * HD + t], acc);
  acc = fmaxf(acc, 0.f);
  red[t] = acc * w2[t];
  __syncthreads();
  for (int off = 64; off > 0; off >>= 1) {
    if (t < off) red[t] += red[t + off];
    __syncthreads();
  }
  if (t == 0) out[g] = red[0] + b2[0];
}

extern "C" void kernel_launch(void* const* d_in, const int* in_sizes, int n_in,
                              void* d_out, int out_size, void* d_ws, size_t ws_size,
                              hipStream_t stream) {
  (void)n_in; (void)ws_size;
  const int*   z      = (const int*)d_in[1];
  const int*   ei     = (const int*)d_in[2];
  const int*   batch  = (const int*)d_in[3];
  const float* emb    = (const float*)d_in[4];
  const float* conv_w = (const float*)d_in[5];
  const float* conv_b = (const float*)d_in[6];
  const float* w1     = (const float*)d_in[7];
  const float* b1     = (const float*)d_in[8];
  const float* w2     = (const float*)d_in[9];
  const float* b2     = (const float*)d_in[10];
  int n = in_sizes[1];
  int E = in_sizes[2] / 2;
  int G = out_size;
  const int* esrc = ei;
  const int* edst = ei + E;

  char* p = (char*)d_ws;
  auto alloc = [&](size_t bytes) { void* r = (void*)p; p += (bytes + 255) / 256 * 256; return r; };
  unsigned* bufA = (unsigned*)alloc((size_t)n * HD * 2);  // half
  unsigned* bufB = (unsigned*)alloc((size_t)n * HD * 2);  // half
  int*   degi   = (int*)alloc((size_t)n * 4);
  float* dinv   = (float*)alloc((size_t)n * 4);
  int*   rowptr = (int*)alloc((size_t)(n + 1) * 4);
  int*   cursor = (int*)alloc((size_t)n * 4);
  int*   col    = (int*)alloc((size_t)E * 4);
  float* nrm    = (float*)alloc((size_t)E * 4);
  int*   bsum   = (int*)alloc(1024 * 4);
  int*   ci     = (int*)alloc((size_t)G * 4);

  int nb1024 = (n + 1023) / 1024;

  k_deg_init<<<(n + 255) / 256, 256, 0, stream>>>(degi, n);
  k_count<<<(E + 255) / 256, 256, 0, stream>>>(edst, E, degi);
  k_dinv<<<(n + 255) / 256, 256, 0, stream>>>(degi, dinv, n);
  k_scan1<<<nb1024, 1024, 0, stream>>>(degi, n, rowptr, bsum);
  k_scan2<<<1, 128, 0, stream>>>(bsum, nb1024);
  k_scan3<<<nb1024, 1024, 0, stream>>>(rowptr, bsum, n, E);
  hipMemsetAsync(cursor, 0, (size_t)n * 4, stream);
  k_fill<<<(E + 255) / 256, 256, 0, stream>>>(esrc, edst, E, rowptr, cursor, dinv, col, nrm);
  k_embed<<<(n * 32 + 255) / 256, 256, 0, stream>>>(z, (const float4*)emb, (uint2*)bufA, n);

  for (int l = 0; l < 3; ++l) {
    k_gemm<<<(n + 63) / 64, 256, 0, stream>>>((const uint2*)bufA, conv_w + (size_t)l * HD * HD,
                                              (uint2*)bufB, n);
    k_agg<<<(n + 3) / 4, 256, 0, stream>>>(bufB, rowptr, col, nrm, dinv,
                                           conv_b + (size_t)l * HD, bufA, n, l < 2 ? 1 : 0);
  }

  k_ci<<<(n + 255) / 256, 256, 0, stream>>>(batch, n, ci);
  k_head<<<G, 128, 0, stream>>>((const __half*)bufA, ci, w1, b1, w2, b2, (float*)d_out, G);
}

// Round 3
// 568.537 us; speedup vs baseline: 1.6160x; 1.2091x over previous
//
#include <hip/hip_runtime.h>
#include <hip/hip_fp16.h>

#define HD 128

__device__ inline unsigned pack_h2(float x, float y) {
  __half2 h = __floats2half2_rn(x, y);
  return __builtin_bit_cast(unsigned, h);
}
__device__ inline float2 up_h2(unsigned u) {
  __half2 h = __builtin_bit_cast(__half2, u);
  return __half22float2(h);
}

__device__ inline void fma8(float* acc, uint4 r, float w) {
  float2 f;
  f = up_h2(r.x); acc[0] = fmaf(w, f.x, acc[0]); acc[1] = fmaf(w, f.y, acc[1]);
  f = up_h2(r.y); acc[2] = fmaf(w, f.x, acc[2]); acc[3] = fmaf(w, f.y, acc[3]);
  f = up_h2(r.z); acc[4] = fmaf(w, f.x, acc[4]); acc[5] = fmaf(w, f.y, acc[5]);
  f = up_h2(r.w); acc[6] = fmaf(w, f.x, acc[6]); acc[7] = fmaf(w, f.y, acc[7]);
}

// ---------------- degree / dinv ----------------
__global__ __launch_bounds__(256) void k_deg_init(int* degi, int n) {
  int i = blockIdx.x * 256 + threadIdx.x;
  if (i < n) degi[i] = 1;  // self-loop
}

__global__ __launch_bounds__(256) void k_count(const int* __restrict__ dst, int E, int* degi) {
  int i = blockIdx.x * 256 + threadIdx.x;
  if (i < E) atomicAdd(&degi[dst[i]], 1);
}

__global__ __launch_bounds__(256) void k_dinv(const int* __restrict__ degi, float* dinv, int n) {
  int i = blockIdx.x * 256 + threadIdx.x;
  if (i < n) dinv[i] = 1.0f / sqrtf((float)degi[i]);
}

// ---------------- exclusive scan of (degi[i]-1) -> rowptr ----------------
__global__ __launch_bounds__(1024) void k_scan1(const int* __restrict__ degi, int n,
                                                int* rowptr, int* bsum) {
  __shared__ int tmp[1024];
  int i = blockIdx.x * 1024 + threadIdx.x;
  int v = (i < n) ? (degi[i] - 1) : 0;
  tmp[threadIdx.x] = v;
  __syncthreads();
  for (int off = 1; off < 1024; off <<= 1) {
    int t = (threadIdx.x >= off) ? tmp[threadIdx.x - off] : 0;
    __syncthreads();
    tmp[threadIdx.x] += t;
    __syncthreads();
  }
  if (i < n) rowptr[i] = tmp[threadIdx.x] - v;
  if (threadIdx.x == 1023) bsum[blockIdx.x] = tmp[1023];
}

__global__ __launch_bounds__(128) void k_scan2(int* bsum, int nb) {
  __shared__ int tmp[128];
  int v = (threadIdx.x < nb) ? bsum[threadIdx.x] : 0;
  tmp[threadIdx.x] = v;
  __syncthreads();
  for (int off = 1; off < 128; off <<= 1) {
    int t = (threadIdx.x >= off) ? tmp[threadIdx.x - off] : 0;
    __syncthreads();
    tmp[threadIdx.x] += t;
    __syncthreads();
  }
  if (threadIdx.x < nb) bsum[threadIdx.x] = tmp[threadIdx.x] - v;
}

__global__ __launch_bounds__(1024) void k_scan3(int* rowptr, const int* __restrict__ bsum,
                                                int n, int Etot) {
  int i = blockIdx.x * 1024 + threadIdx.x;
  if (i < n) rowptr[i] += bsum[blockIdx.x];
  if (i == 0) rowptr[n] = Etot;
}

// ---------------- CSR fill: one 8B scattered store per edge ----------------
__global__ __launch_bounds__(256) void k_fill(const int* __restrict__ src, const int* __restrict__ dst,
                                              int E, const int* __restrict__ rowptr, int* cursor,
                                              const float* __restrict__ dinv,
                                              uint2* __restrict__ pair) {
  int i = blockIdx.x * 256 + threadIdx.x;
  if (i >= E) return;
  int s = src[i], d = dst[i];
  int pos = rowptr[d] + atomicAdd(&cursor[d], 1);
  uint2 pr;
  pr.x = (unsigned)s;
  pr.y = __float_as_uint(dinv[s] * dinv[d]);
  pair[pos] = pr;
}

// ---------------- embedding gather -> half ----------------
__global__ __launch_bounds__(256) void k_embed(const int* __restrict__ z,
                                               const float4* __restrict__ emb,
                                               uint2* __restrict__ xh, int n) {
  int idx = blockIdx.x * 256 + threadIdx.x;
  if (idx >= n * 32) return;
  int node = idx >> 5, q = idx & 31;
  float4 v = emb[(size_t)z[node] * 32 + q];
  uint2 o;
  o.x = pack_h2(v.x, v.y);
  o.y = pack_h2(v.z, v.w);
  xh[idx] = o;
}

// ---------------- GEMM: Yh[n,128] = Xh[n,128] @ W[128,128] (fp32 acc) ----------------
#define FMA4(ACC, S, WV) \
  ACC.x = fmaf(S, WV.x, ACC.x); ACC.y = fmaf(S, WV.y, ACC.y); \
  ACC.z = fmaf(S, WV.z, ACC.z); ACC.w = fmaf(S, WV.w, ACC.w);

__global__ __launch_bounds__(256) void k_gemm(const uint2* __restrict__ Xh,
                                              const float* __restrict__ W,
                                              uint2* __restrict__ Yh, int n) {
  __shared__ float4 Wl[128 * 32];  // 64 KB fp32
  const float4* W4 = (const float4*)W;
  for (int i = threadIdx.x; i < 128 * 32; i += 256) Wl[i] = W4[i];
  __syncthreads();
  int tx = threadIdx.x & 31, ty = threadIdx.x >> 5;
  int rbase = blockIdx.x * 64 + ty * 8;
  float4 acc[8];
#pragma unroll
  for (int r = 0; r < 8; ++r) acc[r] = make_float4(0.f, 0.f, 0.f, 0.f);
  const uint2* Arow[8];
#pragma unroll
  for (int r = 0; r < 8; ++r) {
    int rr = rbase + r;
    if (rr > n - 1) rr = n - 1;  // clamp loads; stores guarded below
    Arow[r] = Xh + (size_t)rr * 32;
  }
  for (int k4 = 0; k4 < 32; ++k4) {
    float4 w0 = Wl[(k4 * 4 + 0) * 32 + tx];
    float4 w1 = Wl[(k4 * 4 + 1) * 32 + tx];
    float4 w2 = Wl[(k4 * 4 + 2) * 32 + tx];
    float4 w3 = Wl[(k4 * 4 + 3) * 32 + tx];
#pragma unroll
    for (int r = 0; r < 8; ++r) {
      uint2 a = Arow[r][k4];
      float2 f01 = up_h2(a.x);
      float2 f23 = up_h2(a.y);
      FMA4(acc[r], f01.x, w0)
      FMA4(acc[r], f01.y, w1)
      FMA4(acc[r], f23.x, w2)
      FMA4(acc[r], f23.y, w3)
    }
  }
#pragma unroll
  for (int r = 0; r < 8; ++r) {
    int rr = rbase + r;
    if (rr < n) {
      uint2 o;
      o.x = pack_h2(acc[r].x, acc[r].y);
      o.y = pack_h2(acc[r].z, acc[r].w);
      Yh[(size_t)rr * 32 + tx] = o;
    }
  }
}

// ------- aggregate: 16 lanes/row (uint4 = 8 halfs), 4 rows/wave, unroll x4 ----------
__global__ __launch_bounds__(256) void k_agg(const uint4* __restrict__ H,
                                             const int* __restrict__ rowptr,
                                             const uint2* __restrict__ pair,
                                             const float* __restrict__ dinv,
                                             const float* __restrict__ bias,
                                             uint4* __restrict__ Out, int n, int relu) {
  int li = threadIdx.x & 15;
  int node = blockIdx.x * 16 + (threadIdx.x >> 4);
  if (node >= n) return;
  float di = dinv[node];
  float w_self = di * di;
  uint4 srow = H[(size_t)node * 16 + li];
  float acc[8] = {0.f, 0.f, 0.f, 0.f, 0.f, 0.f, 0.f, 0.f};
  fma8(acc, srow, w_self);
  int e = rowptr[node], end = rowptr[node + 1];
  for (; e + 3 < end; e += 4) {
    uint2 p0 = pair[e], p1 = pair[e + 1], p2 = pair[e + 2], p3 = pair[e + 3];
    uint4 r0 = H[(size_t)p0.x * 16 + li];
    uint4 r1 = H[(size_t)p1.x * 16 + li];
    uint4 r2 = H[(size_t)p2.x * 16 + li];
    uint4 r3 = H[(size_t)p3.x * 16 + li];
    fma8(acc, r0, __uint_as_float(p0.y));
    fma8(acc, r1, __uint_as_float(p1.y));
    fma8(acc, r2, __uint_as_float(p2.y));
    fma8(acc, r3, __uint_as_float(p3.y));
  }
  for (; e < end; ++e) {
    uint2 p = pair[e];
    uint4 r = H[(size_t)p.x * 16 + li];
    fma8(acc, r, __uint_as_float(p.y));
  }
  float4 b0 = ((const float4*)bias)[2 * li];
  float4 b1 = ((const float4*)bias)[2 * li + 1];
  acc[0] += b0.x; acc[1] += b0.y; acc[2] += b0.z; acc[3] += b0.w;
  acc[4] += b1.x; acc[5] += b1.y; acc[6] += b1.z; acc[7] += b1.w;
  if (relu) {
#pragma unroll
    for (int q = 0; q < 8; ++q) acc[q] = fmaxf(acc[q], 0.f);
  }
  uint4 o;
  o.x = pack_h2(acc[0], acc[1]);
  o.y = pack_h2(acc[2], acc[3]);
  o.z = pack_h2(acc[4], acc[5]);
  o.w = pack_h2(acc[6], acc[7]);
  Out[(size_t)node * 16 + li] = o;
}

// ---------------- center indices ----------------
__global__ __launch_bounds__(256) void k_ci(const int* __restrict__ batch, int n, int* ci) {
  int i = blockIdx.x * 256 + threadIdx.x;
  if (i >= n) return;
  if (i == 0 || batch[i] != batch[i - 1]) ci[batch[i]] = i;
}

// ---------------- head ----------------
__global__ __launch_bounds__(128) void k_head(const __half* __restrict__ X,
                                              const int* __restrict__ ci,
                                              const float* __restrict__ W1,
                                              const float* __restrict__ b1,
                                              const float* __restrict__ w2,
                                              const float* __restrict__ b2,
                                              float* __restrict__ out, int G) {
  __shared__ float xs[HD];
  __shared__ float red[HD];
  int g = blockIdx.x;
  int t = threadIdx.x;
  int c = ci[g];
  xs[t] = __half2float(X[(size_t)c * HD + t]) * __half2float(X[(size_t)(c + 1) * HD + t]);
  __syncthreads();
  float acc = b1[t];
#pragma unroll 8
  for (int k = 0; k < HD; ++k) acc = fmaf(xs[k], W1[k * HD + t], acc);
  acc = fmaxf(acc, 0.f);
  red[t] = acc * w2[t];
  __syncthreads();
  for (int off = 64; off > 0; off >>= 1) {
    if (t < off) red[t] += red[t + off];
    __syncthreads();
  }
  if (t == 0) out[g] = red[0] + b2[0];
}

extern "C" void kernel_launch(void* const* d_in, const int* in_sizes, int n_in,
                              void* d_out, int out_size, void* d_ws, size_t ws_size,
                              hipStream_t stream) {
  (void)n_in; (void)ws_size;
  const int*   z      = (const int*)d_in[1];
  const int*   ei     = (const int*)d_in[2];
  const int*   batch  = (const int*)d_in[3];
  const float* emb    = (const float*)d_in[4];
  const float* conv_w = (const float*)d_in[5];
  const float* conv_b = (const float*)d_in[6];
  const float* w1     = (const float*)d_in[7];
  const float* b1     = (const float*)d_in[8];
  const float* w2     = (const float*)d_in[9];
  const float* b2     = (const float*)d_in[10];
  int n = in_sizes[1];
  int E = in_sizes[2] / 2;
  int G = out_size;
  const int* esrc = ei;
  const int* edst = ei + E;

  char* p = (char*)d_ws;
  auto alloc = [&](size_t bytes) { void* r = (void*)p; p += (bytes + 255) / 256 * 256; return r; };
  unsigned* bufA = (unsigned*)alloc((size_t)n * HD * 2);  // half
  unsigned* bufB = (unsigned*)alloc((size_t)n * HD * 2);  // half
  int*   degi   = (int*)alloc((size_t)n * 4);
  float* dinv   = (float*)alloc((size_t)n * 4);
  int*   rowptr = (int*)alloc((size_t)(n + 1) * 4);
  int*   cursor = (int*)alloc((size_t)n * 4);
  uint2* pair   = (uint2*)alloc((size_t)E * 8);
  int*   bsum   = (int*)alloc(1024 * 4);
  int*   ci     = (int*)alloc((size_t)G * 4);

  int nb1024 = (n + 1023) / 1024;

  k_deg_init<<<(n + 255) / 256, 256, 0, stream>>>(degi, n);
  k_count<<<(E + 255) / 256, 256, 0, stream>>>(edst, E, degi);
  k_dinv<<<(n + 255) / 256, 256, 0, stream>>>(degi, dinv, n);
  k_scan1<<<nb1024, 1024, 0, stream>>>(degi, n, rowptr, bsum);
  k_scan2<<<1, 128, 0, stream>>>(bsum, nb1024);
  k_scan3<<<nb1024, 1024, 0, stream>>>(rowptr, bsum, n, E);
  hipMemsetAsync(cursor, 0, (size_t)n * 4, stream);
  k_fill<<<(E + 255) / 256, 256, 0, stream>>>(esrc, edst, E, rowptr, cursor, dinv, pair);
  k_embed<<<(n * 32 + 255) / 256, 256, 0, stream>>>(z, (const float4*)emb, (uint2*)bufA, n);

  for (int l = 0; l < 3; ++l) {
    k_gemm<<<(n + 63) / 64, 256, 0, stream>>>((const uint2*)bufA, conv_w + (size_t)l * HD * HD,
                                              (uint2*)bufB, n);
    k_agg<<<(n + 15) / 16, 256, 0, stream>>>((const uint4*)bufB, rowptr, pair, dinv,
                                             conv_b + (size_t)l * HD, (uint4*)bufA, n,
                                             l < 2 ? 1 : 0);
  }

  k_ci<<<(n + 255) / 256, 256, 0, stream>>>(batch, n, ci);
  k_head<<<G, 128, 0, stream>>>((const __half*)bufA, ci, w1, b1, w2, b2, (float*)d_out, G);
}

// Round 4
// 403.086 us; speedup vs baseline: 2.2793x; 1.4105x over previous
//
#include <hip/hip_runtime.h>
#include <hip/hip_fp16.h>

#define HD 128

typedef _Float16 half8_t __attribute__((ext_vector_type(8)));
typedef float floatx4 __attribute__((ext_vector_type(4)));

__device__ inline unsigned pack_h2(float x, float y) {
  __half2 h = __floats2half2_rn(x, y);
  return __builtin_bit_cast(unsigned, h);
}
__device__ inline float2 up_h2(unsigned u) {
  __half2 h = __builtin_bit_cast(__half2, u);
  return __half22float2(h);
}

__device__ inline void fma8(float* acc, uint4 r, float w) {
  float2 f;
  f = up_h2(r.x); acc[0] = fmaf(w, f.x, acc[0]); acc[1] = fmaf(w, f.y, acc[1]);
  f = up_h2(r.y); acc[2] = fmaf(w, f.x, acc[2]); acc[3] = fmaf(w, f.y, acc[3]);
  f = up_h2(r.z); acc[4] = fmaf(w, f.x, acc[4]); acc[5] = fmaf(w, f.y, acc[5]);
  f = up_h2(r.w); acc[6] = fmaf(w, f.x, acc[6]); acc[7] = fmaf(w, f.y, acc[7]);
}

// ---------------- degree / dinv ----------------
__global__ __launch_bounds__(256) void k_deg_init(int* degi, int n) {
  int i = blockIdx.x * 256 + threadIdx.x;
  if (i < n) degi[i] = 1;  // self-loop
}

__global__ __launch_bounds__(256) void k_count(const int* __restrict__ dst, int E, int* degi) {
  int i = blockIdx.x * 256 + threadIdx.x;
  if (i < E) atomicAdd(&degi[dst[i]], 1);
}

__global__ __launch_bounds__(256) void k_dinv(const int* __restrict__ degi, float* dinv, int n) {
  int i = blockIdx.x * 256 + threadIdx.x;
  if (i < n) dinv[i] = 1.0f / sqrtf((float)degi[i]);
}

// ---------------- exclusive scan of (degi[i]-1) -> rowptr ----------------
__global__ __launch_bounds__(1024) void k_scan1(const int* __restrict__ degi, int n,
                                                int* rowptr, int* bsum) {
  __shared__ int tmp[1024];
  int i = blockIdx.x * 1024 + threadIdx.x;
  int v = (i < n) ? (degi[i] - 1) : 0;
  tmp[threadIdx.x] = v;
  __syncthreads();
  for (int off = 1; off < 1024; off <<= 1) {
    int t = (threadIdx.x >= off) ? tmp[threadIdx.x - off] : 0;
    __syncthreads();
    tmp[threadIdx.x] += t;
    __syncthreads();
  }
  if (i < n) rowptr[i] = tmp[threadIdx.x] - v;
  if (threadIdx.x == 1023) bsum[blockIdx.x] = tmp[1023];
}

__global__ __launch_bounds__(128) void k_scan2(int* bsum, int nb) {
  __shared__ int tmp[128];
  int v = (threadIdx.x < nb) ? bsum[threadIdx.x] : 0;
  tmp[threadIdx.x] = v;
  __syncthreads();
  for (int off = 1; off < 128; off <<= 1) {
    int t = (threadIdx.x >= off) ? tmp[threadIdx.x - off] : 0;
    __syncthreads();
    tmp[threadIdx.x] += t;
    __syncthreads();
  }
  if (threadIdx.x < nb) bsum[threadIdx.x] = tmp[threadIdx.x] - v;
}

__global__ __launch_bounds__(1024) void k_scan3(int* rowptr, const int* __restrict__ bsum,
                                                int n, int Etot) {
  int i = blockIdx.x * 1024 + threadIdx.x;
  if (i < n) rowptr[i] += bsum[blockIdx.x];
  if (i == 0) rowptr[n] = Etot;
}

// ---------------- CSR fill: one 8B scattered store per edge ----------------
__global__ __launch_bounds__(256) void k_fill(const int* __restrict__ src, const int* __restrict__ dst,
                                              int E, const int* __restrict__ rowptr, int* cursor,
                                              const float* __restrict__ dinv,
                                              uint2* __restrict__ pair) {
  int i = blockIdx.x * 256 + threadIdx.x;
  if (i >= E) return;
  int s = src[i], d = dst[i];
  int pos = rowptr[d] + atomicAdd(&cursor[d], 1);
  uint2 pr;
  pr.x = (unsigned)s;
  pr.y = __float_as_uint(dinv[s] * dinv[d]);
  pair[pos] = pr;
}

// ---------------- embedding gather -> half ----------------
__global__ __launch_bounds__(256) void k_embed(const int* __restrict__ z,
                                               const float4* __restrict__ emb,
                                               uint2* __restrict__ xh, int n) {
  int idx = blockIdx.x * 256 + threadIdx.x;
  if (idx >= n * 32) return;
  int node = idx >> 5, q = idx & 31;
  float4 v = emb[(size_t)z[node] * 32 + q];
  uint2 o;
  o.x = pack_h2(v.x, v.y);
  o.y = pack_h2(v.z, v.w);
  xh[idx] = o;
}

// ---------------- W fragment pre-pack: fp32 [3][128][128] -> frag-order fp16 ----------------
// frag element: layer, chalf(2), c4(4), s(4), lane(64) -> 8 halfs (uint4)
// value[j] = W[k = s*32 + (lane>>4)*8 + j][col = chalf*64 + c4*16 + (lane&15)]
__global__ __launch_bounds__(256) void k_wprep(const float* __restrict__ conv_w,
                                               uint4* __restrict__ wfrag) {
  int t = blockIdx.x * 256 + threadIdx.x;
  if (t >= 3 * 2 * 4 * 4 * 64) return;
  int lane = t & 63;
  int s = (t >> 6) & 3;
  int c4 = (t >> 8) & 3;
  int chalf = (t >> 10) & 1;
  int layer = t >> 11;
  int col = chalf * 64 + c4 * 16 + (lane & 15);
  int k0 = s * 32 + (lane >> 4) * 8;
  const float* W = conv_w + (size_t)layer * HD * HD;
  unsigned u[4];
#pragma unroll
  for (int j = 0; j < 4; ++j)
    u[j] = pack_h2(W[(size_t)(k0 + 2 * j) * HD + col], W[(size_t)(k0 + 2 * j + 1) * HD + col]);
  uint4 o; o.x = u[0]; o.y = u[1]; o.z = u[2]; o.w = u[3];
  wfrag[t] = o;
}

// ---------------- MFMA GEMM: Yh[n,128] = Xh[n,128] @ W (frag-packed) ----------------
// wave gw: chalf = gw&1 (64 output cols), rowblocks rb = gw>>1, stride nwaves/2
__global__ __launch_bounds__(256) void k_gemm_mfma(const uint4* __restrict__ Xh,   // 16 uint4/row
                                                   const uint4* __restrict__ wfrag, // this layer
                                                   uint2* __restrict__ Yh,          // 32 uint2/row
                                                   int n, int nwaves) {
  int lane = threadIdx.x & 63;
  int gw = blockIdx.x * 4 + (threadIdx.x >> 6);
  int chalf = gw & 1;
  int nrb = (n + 15) >> 4;

  half8_t wf[16];
#pragma unroll
  for (int i = 0; i < 16; ++i) {
    // i = c4*4 + s
    uint4 t = wfrag[((chalf * 4 + (i >> 2)) * 4 + (i & 3)) * 64 + lane];
    wf[i] = __builtin_bit_cast(half8_t, t);
  }

  for (int rb = gw >> 1; rb < nrb; rb += (nwaves >> 1)) {
    int row0 = rb * 16;
    int xr = row0 + (lane & 15);
    if (xr > n - 1) xr = n - 1;
    const uint4* xrow = Xh + (size_t)xr * 16;
    half8_t bf[4];
#pragma unroll
    for (int s = 0; s < 4; ++s)
      bf[s] = __builtin_bit_cast(half8_t, xrow[s * 4 + (lane >> 4)]);
    floatx4 acc[4];
#pragma unroll
    for (int c4 = 0; c4 < 4; ++c4) acc[c4] = (floatx4){0.f, 0.f, 0.f, 0.f};
#pragma unroll
    for (int s = 0; s < 4; ++s) {
#pragma unroll
      for (int c4 = 0; c4 < 4; ++c4)
        acc[c4] = __builtin_amdgcn_mfma_f32_16x16x32_f16(wf[c4 * 4 + s], bf[s], acc[c4], 0, 0, 0);
    }
    int orow = row0 + (lane & 15);
    if (orow < n) {
#pragma unroll
      for (int c4 = 0; c4 < 4; ++c4) {
        int colbase = chalf * 64 + c4 * 16 + (lane >> 4) * 4;  // 4 consecutive output cols
        uint2 o;
        o.x = pack_h2(acc[c4][0], acc[c4][1]);
        o.y = pack_h2(acc[c4][2], acc[c4][3]);
        Yh[(size_t)orow * 32 + (colbase >> 2)] = o;
      }
    }
  }
}

// ------- aggregate: 16 lanes/row (uint4 = 8 halfs), 4 rows/wave, unroll x4 ----------
__global__ __launch_bounds__(256) void k_agg(const uint4* __restrict__ H,
                                             const int* __restrict__ rowptr,
                                             const uint2* __restrict__ pair,
                                             const float* __restrict__ dinv,
                                             const float* __restrict__ bias,
                                             uint4* __restrict__ Out, int n, int relu) {
  int li = threadIdx.x & 15;
  int node = blockIdx.x * 16 + (threadIdx.x >> 4);
  if (node >= n) return;
  float di = dinv[node];
  float w_self = di * di;
  uint4 srow = H[(size_t)node * 16 + li];
  float acc[8] = {0.f, 0.f, 0.f, 0.f, 0.f, 0.f, 0.f, 0.f};
  fma8(acc, srow, w_self);
  int e = rowptr[node], end = rowptr[node + 1];
  for (; e + 3 < end; e += 4) {
    uint2 p0 = pair[e], p1 = pair[e + 1], p2 = pair[e + 2], p3 = pair[e + 3];
    uint4 r0 = H[(size_t)p0.x * 16 + li];
    uint4 r1 = H[(size_t)p1.x * 16 + li];
    uint4 r2 = H[(size_t)p2.x * 16 + li];
    uint4 r3 = H[(size_t)p3.x * 16 + li];
    fma8(acc, r0, __uint_as_float(p0.y));
    fma8(acc, r1, __uint_as_float(p1.y));
    fma8(acc, r2, __uint_as_float(p2.y));
    fma8(acc, r3, __uint_as_float(p3.y));
  }
  for (; e < end; ++e) {
    uint2 p = pair[e];
    uint4 r = H[(size_t)p.x * 16 + li];
    fma8(acc, r, __uint_as_float(p.y));
  }
  float4 b0 = ((const float4*)bias)[2 * li];
  float4 b1 = ((const float4*)bias)[2 * li + 1];
  acc[0] += b0.x; acc[1] += b0.y; acc[2] += b0.z; acc[3] += b0.w;
  acc[4] += b1.x; acc[5] += b1.y; acc[6] += b1.z; acc[7] += b1.w;
  if (relu) {
#pragma unroll
    for (int q = 0; q < 8; ++q) acc[q] = fmaxf(acc[q], 0.f);
  }
  uint4 o;
  o.x = pack_h2(acc[0], acc[1]);
  o.y = pack_h2(acc[2], acc[3]);
  o.z = pack_h2(acc[4], acc[5]);
  o.w = pack_h2(acc[6], acc[7]);
  Out[(size_t)node * 16 + li] = o;
}

// ---------------- center indices ----------------
__global__ __launch_bounds__(256) void k_ci(const int* __restrict__ batch, int n, int* ci) {
  int i = blockIdx.x * 256 + threadIdx.x;
  if (i >= n) return;
  if (i == 0 || batch[i] != batch[i - 1]) ci[batch[i]] = i;
}

// ---------------- head ----------------
__global__ __launch_bounds__(128) void k_head(const __half* __restrict__ X,
                                              const int* __restrict__ ci,
                                              const float* __restrict__ W1,
                                              const float* __restrict__ b1,
                                              const float* __restrict__ w2,
                                              const float* __restrict__ b2,
                                              float* __restrict__ out, int G) {
  __shared__ float xs[HD];
  __shared__ float red[HD];
  int g = blockIdx.x;
  int t = threadIdx.x;
  int c = ci[g];
  xs[t] = __half2float(X[(size_t)c * HD + t]) * __half2float(X[(size_t)(c + 1) * HD + t]);
  __syncthreads();
  float acc = b1[t];
#pragma unroll 8
  for (int k = 0; k < HD; ++k) acc = fmaf(xs[k], W1[k * HD + t], acc);
  acc = fmaxf(acc, 0.f);
  red[t] = acc * w2[t];
  __syncthreads();
  for (int off = 64; off > 0; off >>= 1) {
    if (t < off) red[t] += red[t + off];
    __syncthreads();
  }
  if (t == 0) out[g] = red[0] + b2[0];
}

extern "C" void kernel_launch(void* const* d_in, const int* in_sizes, int n_in,
                              void* d_out, int out_size, void* d_ws, size_t ws_size,
                              hipStream_t stream) {
  (void)n_in; (void)ws_size;
  const int*   z      = (const int*)d_in[1];
  const int*   ei     = (const int*)d_in[2];
  const int*   batch  = (const int*)d_in[3];
  const float* emb    = (const float*)d_in[4];
  const float* conv_w = (const float*)d_in[5];
  const float* conv_b = (const float*)d_in[6];
  const float* w1     = (const float*)d_in[7];
  const float* b1     = (const float*)d_in[8];
  const float* w2     = (const float*)d_in[9];
  const float* b2     = (const float*)d_in[10];
  int n = in_sizes[1];
  int E = in_sizes[2] / 2;
  int G = out_size;
  const int* esrc = ei;
  const int* edst = ei + E;

  char* p = (char*)d_ws;
  auto alloc = [&](size_t bytes) { void* r = (void*)p; p += (bytes + 255) / 256 * 256; return r; };
  unsigned* bufA = (unsigned*)alloc((size_t)n * HD * 2);  // half
  unsigned* bufB = (unsigned*)alloc((size_t)n * HD * 2);  // half
  int*   degi   = (int*)alloc((size_t)n * 4);
  float* dinv   = (float*)alloc((size_t)n * 4);
  int*   rowptr = (int*)alloc((size_t)(n + 1) * 4);
  int*   cursor = (int*)alloc((size_t)n * 4);
  uint2* pair   = (uint2*)alloc((size_t)E * 8);
  uint4* wfrag  = (uint4*)alloc((size_t)3 * 2048 * 16);
  int*   bsum   = (int*)alloc(1024 * 4);
  int*   ci     = (int*)alloc((size_t)G * 4);

  int nb1024 = (n + 1023) / 1024;

  k_deg_init<<<(n + 255) / 256, 256, 0, stream>>>(degi, n);
  k_count<<<(E + 255) / 256, 256, 0, stream>>>(edst, E, degi);
  k_dinv<<<(n + 255) / 256, 256, 0, stream>>>(degi, dinv, n);
  k_scan1<<<nb1024, 1024, 0, stream>>>(degi, n, rowptr, bsum);
  k_scan2<<<1, 128, 0, stream>>>(bsum, nb1024);
  k_scan3<<<nb1024, 1024, 0, stream>>>(rowptr, bsum, n, E);
  hipMemsetAsync(cursor, 0, (size_t)n * 4, stream);
  k_fill<<<(E + 255) / 256, 256, 0, stream>>>(esrc, edst, E, rowptr, cursor, dinv, pair);
  k_wprep<<<24, 256, 0, stream>>>(conv_w, wfrag);
  k_embed<<<(n * 32 + 255) / 256, 256, 0, stream>>>(z, (const float4*)emb, (uint2*)bufA, n);

  const int nwaves = 4096;  // 1024 blocks * 4 waves
  for (int l = 0; l < 3; ++l) {
    k_gemm_mfma<<<nwaves / 4, 256, 0, stream>>>((const uint4*)bufA, wfrag + (size_t)l * 2048,
                                                (uint2*)bufB, n, nwaves);
    k_agg<<<(n + 15) / 16, 256, 0, stream>>>((const uint4*)bufB, rowptr, pair, dinv,
                                             conv_b + (size_t)l * HD, (uint4*)bufA, n,
                                             l < 2 ? 1 : 0);
  }

  k_ci<<<(n + 255) / 256, 256, 0, stream>>>(batch, n, ci);
  k_head<<<G, 128, 0, stream>>>((const __half*)bufA, ci, w1, b1, w2, b2, (float*)d_out, G);
}

// Round 5
// 342.032 us; speedup vs baseline: 2.6862x; 1.1785x over previous
//
#include <hip/hip_runtime.h>
#include <hip/hip_fp16.h>

#define HD 128
#define BSH 9              // 512 dst-nodes per bucket
#define NBLKA 128          // phase-A persistent blocks
#define CAP 160            // per (block,bucket) cell capacity (mean ~64)

typedef _Float16 half8_t __attribute__((ext_vector_type(8)));
typedef float floatx4 __attribute__((ext_vector_type(4)));

__device__ inline unsigned pack_h2(float x, float y) {
  __half2 h = __floats2half2_rn(x, y);
  return __builtin_bit_cast(unsigned, h);
}
__device__ inline float2 up_h2(unsigned u) {
  __half2 h = __builtin_bit_cast(__half2, u);
  return __half22float2(h);
}

__device__ inline void fma8(float* acc, uint4 r, float w) {
  float2 f;
  f = up_h2(r.x); acc[0] = fmaf(w, f.x, acc[0]); acc[1] = fmaf(w, f.y, acc[1]);
  f = up_h2(r.y); acc[2] = fmaf(w, f.x, acc[2]); acc[3] = fmaf(w, f.y, acc[3]);
  f = up_h2(r.z); acc[4] = fmaf(w, f.x, acc[4]); acc[5] = fmaf(w, f.y, acc[5]);
  f = up_h2(r.w); acc[6] = fmaf(w, f.x, acc[6]); acc[7] = fmaf(w, f.y, acc[7]);
}

// ---------- phase A: block-private bucket append (no global atomics) ----------
__global__ __launch_bounds__(256) void k_bucketA(const int* __restrict__ src,
                                                 const int* __restrict__ dst, int E, int nbuck,
                                                 unsigned* __restrict__ bpool,
                                                 int* __restrict__ counts) {
  __shared__ int cnt[512];
  for (int i = threadIdx.x; i < nbuck; i += 256) cnt[i] = 0;
  __syncthreads();
  int blk = blockIdx.x;
  int chunk = (E + NBLKA - 1) / NBLKA;
  int lo = blk * chunk, hi = min(E, lo + chunk);
  for (int i = lo + threadIdx.x; i < hi; i += 256) {
    int s = src[i], d = dst[i];
    int b = d >> BSH;
    int c = atomicAdd(&cnt[b], 1);
    if (c < CAP)
      bpool[((size_t)b * NBLKA + blk) * CAP + c] =
          ((unsigned)(d & ((1 << BSH) - 1)) << 23) | (unsigned)s;
  }
  __syncthreads();
  for (int b = threadIdx.x; b < nbuck; b += 256) counts[(size_t)b * NBLKA + blk] = cnt[b];
}

// ---------- phase B1: per-bucket degree histogram -> degi (with self-loop) ----------
__global__ __launch_bounds__(256) void k_bhist(const unsigned* __restrict__ bpool,
                                               const int* __restrict__ counts,
                                               int n, int* __restrict__ degi) {
  __shared__ int hist[1 << BSH];
  __shared__ int ccache[NBLKA];
  int b = blockIdx.x;
  int base = b << BSH;
  int nn = min(1 << BSH, n - base);
  for (int i = threadIdx.x; i < nn; i += 256) hist[i] = 0;
  for (int i = threadIdx.x; i < NBLKA; i += 256)
    ccache[i] = min(counts[(size_t)b * NBLKA + i], CAP);
  __syncthreads();
  int w = threadIdx.x >> 6, lane = threadIdx.x & 63;
  for (int blk = w; blk < NBLKA; blk += 4) {
    int c = ccache[blk];
    const unsigned* seg = bpool + ((size_t)b * NBLKA + blk) * CAP;
    for (int i = lane; i < c; i += 64) atomicAdd(&hist[seg[i] >> 23], 1);
  }
  __syncthreads();
  for (int i = threadIdx.x; i < nn; i += 256) degi[base + i] = hist[i] + 1;
}

// ---------- dinv ----------
__global__ __launch_bounds__(256) void k_dinv(const int* __restrict__ degi, float* dinv, int n) {
  int i = blockIdx.x * 256 + threadIdx.x;
  if (i < n) dinv[i] = 1.0f / sqrtf((float)degi[i]);
}

// ---------- exclusive scan of (degi[i]-1) -> rowptr ----------
__global__ __launch_bounds__(1024) void k_scan1(const int* __restrict__ degi, int n,
                                                int* rowptr, int* bsum) {
  __shared__ int tmp[1024];
  int i = blockIdx.x * 1024 + threadIdx.x;
  int v = (i < n) ? (degi[i] - 1) : 0;
  tmp[threadIdx.x] = v;
  __syncthreads();
  for (int off = 1; off < 1024; off <<= 1) {
    int t = (threadIdx.x >= off) ? tmp[threadIdx.x - off] : 0;
    __syncthreads();
    tmp[threadIdx.x] += t;
    __syncthreads();
  }
  if (i < n) rowptr[i] = tmp[threadIdx.x] - v;
  if (threadIdx.x == 1023) bsum[blockIdx.x] = tmp[1023];
}

__global__ __launch_bounds__(128) void k_scan2(int* bsum, int nb) {
  __shared__ int tmp[128];
  int v = (threadIdx.x < nb) ? bsum[threadIdx.x] : 0;
  tmp[threadIdx.x] = v;
  __syncthreads();
  for (int off = 1; off < 128; off <<= 1) {
    int t = (threadIdx.x >= off) ? tmp[threadIdx.x - off] : 0;
    __syncthreads();
    tmp[threadIdx.x] += t;
    __syncthreads();
  }
  if (threadIdx.x < nb) bsum[threadIdx.x] = tmp[threadIdx.x] - v;
}

__global__ __launch_bounds__(1024) void k_scan3(int* rowptr, const int* __restrict__ bsum,
                                                int n, int Etot) {
  int i = blockIdx.x * 1024 + threadIdx.x;
  if (i < n) rowptr[i] += bsum[blockIdx.x];
  if (i == 0) rowptr[n] = Etot;
}

// ---------- phase B2: per-bucket CSR fill (LDS cursors, L2-local writes) ----------
__global__ __launch_bounds__(256) void k_bfill(const unsigned* __restrict__ bpool,
                                               const int* __restrict__ counts,
                                               const int* __restrict__ rowptr,
                                               const float* __restrict__ dinv,
                                               int n, uint2* __restrict__ pair) {
  __shared__ int cur[1 << BSH];
  __shared__ float dloc[1 << BSH];
  __shared__ int ccache[NBLKA];
  int b = blockIdx.x;
  int base = b << BSH;
  int nn = min(1 << BSH, n - base);
  for (int i = threadIdx.x; i < nn; i += 256) {
    cur[i] = rowptr[base + i];
    dloc[i] = dinv[base + i];
  }
  for (int i = threadIdx.x; i < NBLKA; i += 256)
    ccache[i] = min(counts[(size_t)b * NBLKA + i], CAP);
  __syncthreads();
  int w = threadIdx.x >> 6, lane = threadIdx.x & 63;
  for (int blk = w; blk < NBLKA; blk += 4) {
    int c = ccache[blk];
    const unsigned* seg = bpool + ((size_t)b * NBLKA + blk) * CAP;
    for (int i = lane; i < c; i += 64) {
      unsigned pk = seg[i];
      int dl = pk >> 23;
      int s = pk & 0x7FFFFF;
      int pos = atomicAdd(&cur[dl], 1);
      uint2 pr;
      pr.x = (unsigned)s;
      pr.y = __float_as_uint(dinv[s] * dloc[dl]);
      pair[pos] = pr;
    }
  }
}

// ---------- embedding gather -> half ----------
__global__ __launch_bounds__(256) void k_embed(const int* __restrict__ z,
                                               const float4* __restrict__ emb,
                                               uint2* __restrict__ xh, int n) {
  int idx = blockIdx.x * 256 + threadIdx.x;
  if (idx >= n * 32) return;
  int node = idx >> 5, q = idx & 31;
  float4 v = emb[(size_t)z[node] * 32 + q];
  uint2 o;
  o.x = pack_h2(v.x, v.y);
  o.y = pack_h2(v.z, v.w);
  xh[idx] = o;
}

// ---------- W fragment pre-pack ----------
__global__ __launch_bounds__(256) void k_wprep(const float* __restrict__ conv_w,
                                               uint4* __restrict__ wfrag) {
  int t = blockIdx.x * 256 + threadIdx.x;
  if (t >= 3 * 2 * 4 * 4 * 64) return;
  int lane = t & 63;
  int s = (t >> 6) & 3;
  int c4 = (t >> 8) & 3;
  int chalf = (t >> 10) & 1;
  int layer = t >> 11;
  int col = chalf * 64 + c4 * 16 + (lane & 15);
  int k0 = s * 32 + (lane >> 4) * 8;
  const float* W = conv_w + (size_t)layer * HD * HD;
  unsigned u[4];
#pragma unroll
  for (int j = 0; j < 4; ++j)
    u[j] = pack_h2(W[(size_t)(k0 + 2 * j) * HD + col], W[(size_t)(k0 + 2 * j + 1) * HD + col]);
  uint4 o; o.x = u[0]; o.y = u[1]; o.z = u[2]; o.w = u[3];
  wfrag[t] = o;
}

// ---------- MFMA GEMM ----------
__global__ __launch_bounds__(256) void k_gemm_mfma(const uint4* __restrict__ Xh,
                                                   const uint4* __restrict__ wfrag,
                                                   uint2* __restrict__ Yh,
                                                   int n, int nwaves) {
  int lane = threadIdx.x & 63;
  int gw = blockIdx.x * 4 + (threadIdx.x >> 6);
  int chalf = gw & 1;
  int nrb = (n + 15) >> 4;

  half8_t wf[16];
#pragma unroll
  for (int i = 0; i < 16; ++i) {
    uint4 t = wfrag[((chalf * 4 + (i >> 2)) * 4 + (i & 3)) * 64 + lane];
    wf[i] = __builtin_bit_cast(half8_t, t);
  }

  for (int rb = gw >> 1; rb < nrb; rb += (nwaves >> 1)) {
    int row0 = rb * 16;
    int xr = row0 + (lane & 15);
    if (xr > n - 1) xr = n - 1;
    const uint4* xrow = Xh + (size_t)xr * 16;
    half8_t bf[4];
#pragma unroll
    for (int s = 0; s < 4; ++s)
      bf[s] = __builtin_bit_cast(half8_t, xrow[s * 4 + (lane >> 4)]);
    floatx4 acc[4];
#pragma unroll
    for (int c4 = 0; c4 < 4; ++c4) acc[c4] = (floatx4){0.f, 0.f, 0.f, 0.f};
#pragma unroll
    for (int s = 0; s < 4; ++s) {
#pragma unroll
      for (int c4 = 0; c4 < 4; ++c4)
        acc[c4] = __builtin_amdgcn_mfma_f32_16x16x32_f16(wf[c4 * 4 + s], bf[s], acc[c4], 0, 0, 0);
    }
    int orow = row0 + (lane & 15);
    if (orow < n) {
#pragma unroll
      for (int c4 = 0; c4 < 4; ++c4) {
        int colbase = chalf * 64 + c4 * 16 + (lane >> 4) * 4;
        uint2 o;
        o.x = pack_h2(acc[c4][0], acc[c4][1]);
        o.y = pack_h2(acc[c4][2], acc[c4][3]);
        Yh[(size_t)orow * 32 + (colbase >> 2)] = o;
      }
    }
  }
}

// ---------- aggregate ----------
__global__ __launch_bounds__(256) void k_agg(const uint4* __restrict__ H,
                                             const int* __restrict__ rowptr,
                                             const uint2* __restrict__ pair,
                                             const float* __restrict__ dinv,
                                             const float* __restrict__ bias,
                                             uint4* __restrict__ Out, int n, int relu) {
  int li = threadIdx.x & 15;
  int node = blockIdx.x * 16 + (threadIdx.x >> 4);
  if (node >= n) return;
  float di = dinv[node];
  float w_self = di * di;
  uint4 srow = H[(size_t)node * 16 + li];
  float acc[8] = {0.f, 0.f, 0.f, 0.f, 0.f, 0.f, 0.f, 0.f};
  fma8(acc, srow, w_self);
  int e = rowptr[node], end = rowptr[node + 1];
  for (; e + 3 < end; e += 4) {
    uint2 p0 = pair[e], p1 = pair[e + 1], p2 = pair[e + 2], p3 = pair[e + 3];
    uint4 r0 = H[(size_t)p0.x * 16 + li];
    uint4 r1 = H[(size_t)p1.x * 16 + li];
    uint4 r2 = H[(size_t)p2.x * 16 + li];
    uint4 r3 = H[(size_t)p3.x * 16 + li];
    fma8(acc, r0, __uint_as_float(p0.y));
    fma8(acc, r1, __uint_as_float(p1.y));
    fma8(acc, r2, __uint_as_float(p2.y));
    fma8(acc, r3, __uint_as_float(p3.y));
  }
  for (; e < end; ++e) {
    uint2 p = pair[e];
    uint4 r = H[(size_t)p.x * 16 + li];
    fma8(acc, r, __uint_as_float(p.y));
  }
  float4 b0 = ((const float4*)bias)[2 * li];
  float4 b1 = ((const float4*)bias)[2 * li + 1];
  acc[0] += b0.x; acc[1] += b0.y; acc[2] += b0.z; acc[3] += b0.w;
  acc[4] += b1.x; acc[5] += b1.y; acc[6] += b1.z; acc[7] += b1.w;
  if (relu) {
#pragma unroll
    for (int q = 0; q < 8; ++q) acc[q] = fmaxf(acc[q], 0.f);
  }
  uint4 o;
  o.x = pack_h2(acc[0], acc[1]);
  o.y = pack_h2(acc[2], acc[3]);
  o.z = pack_h2(acc[4], acc[5]);
  o.w = pack_h2(acc[6], acc[7]);
  Out[(size_t)node * 16 + li] = o;
}

// ---------- center indices ----------
__global__ __launch_bounds__(256) void k_ci(const int* __restrict__ batch, int n, int* ci) {
  int i = blockIdx.x * 256 + threadIdx.x;
  if (i >= n) return;
  if (i == 0 || batch[i] != batch[i - 1]) ci[batch[i]] = i;
}

// ---------- head ----------
__global__ __launch_bounds__(128) void k_head(const __half* __restrict__ X,
                                              const int* __restrict__ ci,
                                              const float* __restrict__ W1,
                                              const float* __restrict__ b1,
                                              const float* __restrict__ w2,
                                              const float* __restrict__ b2,
                                              float* __restrict__ out, int G) {
  __shared__ float xs[HD];
  __shared__ float red[HD];
  int g = blockIdx.x;
  int t = threadIdx.x;
  int c = ci[g];
  xs[t] = __half2float(X[(size_t)c * HD + t]) * __half2float(X[(size_t)(c + 1) * HD + t]);
  __syncthreads();
  float acc = b1[t];
#pragma unroll 8
  for (int k = 0; k < HD; ++k) acc = fmaf(xs[k], W1[k * HD + t], acc);
  acc = fmaxf(acc, 0.f);
  red[t] = acc * w2[t];
  __syncthreads();
  for (int off = 64; off > 0; off >>= 1) {
    if (t < off) red[t] += red[t + off];
    __syncthreads();
  }
  if (t == 0) out[g] = red[0] + b2[0];
}

extern "C" void kernel_launch(void* const* d_in, const int* in_sizes, int n_in,
                              void* d_out, int out_size, void* d_ws, size_t ws_size,
                              hipStream_t stream) {
  (void)n_in; (void)ws_size;
  const int*   z      = (const int*)d_in[1];
  const int*   ei     = (const int*)d_in[2];
  const int*   batch  = (const int*)d_in[3];
  const float* emb    = (const float*)d_in[4];
  const float* conv_w = (const float*)d_in[5];
  const float* conv_b = (const float*)d_in[6];
  const float* w1     = (const float*)d_in[7];
  const float* b1     = (const float*)d_in[8];
  const float* w2     = (const float*)d_in[9];
  const float* b2     = (const float*)d_in[10];
  int n = in_sizes[1];
  int E = in_sizes[2] / 2;
  int G = out_size;
  const int* esrc = ei;
  const int* edst = ei + E;
  int nbuck = (n + (1 << BSH) - 1) >> BSH;

  char* p = (char*)d_ws;
  auto alloc = [&](size_t bytes) { void* r = (void*)p; p += (bytes + 255) / 256 * 256; return r; };
  unsigned* bufA   = (unsigned*)alloc((size_t)n * HD * 2);  // half
  unsigned* bufB   = (unsigned*)alloc((size_t)n * HD * 2);  // half
  int*      degi   = (int*)alloc((size_t)n * 4);
  float*    dinv   = (float*)alloc((size_t)n * 4);
  int*      rowptr = (int*)alloc((size_t)(n + 1) * 4);
  uint2*    pair   = (uint2*)alloc((size_t)E * 8);
  uint4*    wfrag  = (uint4*)alloc((size_t)3 * 2048 * 16);
  int*      bsum   = (int*)alloc(1024 * 4);
  int*      ci     = (int*)alloc((size_t)G * 4);
  unsigned* bpool  = (unsigned*)alloc((size_t)nbuck * NBLKA * CAP * 4);
  int*      counts = (int*)alloc((size_t)nbuck * NBLKA * 4);

  int nb1024 = (n + 1023) / 1024;

  k_bucketA<<<NBLKA, 256, 0, stream>>>(esrc, edst, E, nbuck, bpool, counts);
  k_bhist<<<nbuck, 256, 0, stream>>>(bpool, counts, n, degi);
  k_dinv<<<(n + 255) / 256, 256, 0, stream>>>(degi, dinv, n);
  k_scan1<<<nb1024, 1024, 0, stream>>>(degi, n, rowptr, bsum);
  k_scan2<<<1, 128, 0, stream>>>(bsum, nb1024);
  k_scan3<<<nb1024, 1024, 0, stream>>>(rowptr, bsum, n, E);
  k_bfill<<<nbuck, 256, 0, stream>>>(bpool, counts, rowptr, dinv, n, pair);
  k_wprep<<<24, 256, 0, stream>>>(conv_w, wfrag);
  k_embed<<<(n * 32 + 255) / 256, 256, 0, stream>>>(z, (const float4*)emb, (uint2*)bufA, n);

  const int nwaves = 4096;
  for (int l = 0; l < 3; ++l) {
    k_gemm_mfma<<<nwaves / 4, 256, 0, stream>>>((const uint4*)bufA, wfrag + (size_t)l * 2048,
                                                (uint2*)bufB, n, nwaves);
    k_agg<<<(n + 15) / 16, 256, 0, stream>>>((const uint4*)bufB, rowptr, pair, dinv,
                                             conv_b + (size_t)l * HD, (uint4*)bufA, n,
                                             l < 2 ? 1 : 0);
  }

  k_ci<<<(n + 255) / 256, 256, 0, stream>>>(batch, n, ci);
  k_head<<<G, 128, 0, stream>>>((const __half*)bufA, ci, w1, b1, w2, b2, (float*)d_out, G);
}